// Round 2
// baseline (448.741 us; speedup 1.0000x reference)
//
#include <hip/hip_runtime.h>
#include <hip/hip_bf16.h>

#define K_IN 2624     // 2048 + 512 + 64
#define NSTEP 82      // K-steps of 32 (prep granularity == pipeline chunk)
#define NCHUNK 82     // lstm pipeline chunks of 32 k

typedef __attribute__((ext_vector_type(8))) short short8;
typedef __attribute__((ext_vector_type(4))) float float4_t;

__device__ __forceinline__ short f2bf(float f) {
    union { __hip_bfloat16 b; short s; } u;
    u.b = __float2bfloat16(f);
    return u.s;
}

__device__ __forceinline__ float sigmoid_fast(float x) {
    return 1.f / (1.f + __expf(-x));
}

__device__ __forceinline__ float tanh_fast(float x) {
    float e = __expf(-2.f * fabsf(x));
    float t = (1.f - e) / (1.f + e);
    return copysignf(t, x);
}

// global -> LDS async DMA, 16 B/lane (global_load_lds_dwordx4).
// LDS dest is wave-uniform base (HW adds lane*16); global src is per-lane.
__device__ __forceinline__ void async16(const void* g, void* l) {
    __builtin_amdgcn_global_load_lds(
        (__attribute__((address_space(1))) void*)g,
        (__attribute__((address_space(3))) void*)l, 16, 0, 0);
}

// ---------------------------------------------------------------------------
// prep: pack fused weight [Wi;Wh] (K_IN x 256, fp32, k-major) into
// MFMA-B-fragment order, bf16:
//   Wt2[kstep s][nb][lane][8elem]: lane l holds B[k=s*32+(l>>4)*8+j][n=nb*16+(l&15)]
// Also bsum[n] = bi[n]+bh[n].
// ---------------------------------------------------------------------------
__global__ void prep_kernel(const float* __restrict__ Wi, const float* __restrict__ bi,
                            const float* __restrict__ Wh, const float* __restrict__ bh,
                            short* __restrict__ Wt2, float* __restrict__ bsum) {
    __shared__ short tile[32][264];   // +8 pad
    const int t = threadIdx.x;
    const int kb = blockIdx.x;
    const int k0 = kb * 32;

#pragma unroll 8
    for (int j = 0; j < 32; ++j) {
        int k = k0 + j;
        float v = (k < 2560) ? Wi[(size_t)k * 256 + t]
                             : Wh[(size_t)(k - 2560) * 256 + t];
        tile[j][t] = f2bf(v);
    }
    if (kb == 0) bsum[t] = bi[t] + bh[t];
    __syncthreads();

#pragma unroll
    for (int c = 0; c < 4; ++c) {
        int idx = c * 256 + t;          // 0..1023 = nb*64 + lane
        int lane = idx & 63;
        int nb = idx >> 6;
        int n = nb * 16 + (lane & 15);
        int j0 = (lane >> 4) * 8;
        short8 v;
#pragma unroll
        for (int j = 0; j < 8; ++j) v[j] = tile[j0 + j][n];
        *reinterpret_cast<short8*>(Wt2 + (size_t)kb * 8192 + (size_t)idx * 8) = v;
    }
}

// ---------------------------------------------------------------------------
// Fused GEMM + LSTM, round 5: gate-split waves + ring-3 + ONE barrier/chunk.
// 512 blocks x 256 threads (4 waves, 2 blocks/CU, LDS 72 KB).
// Wave w owns ALL 64 rows x n-frags {w, w+4, w+8, w+12} (col group w*16 of
// each gate) -> per chunk: 8 A ds_reads + 4 B ds_reads + 16 MFMA; the four
// gates of hidden col n0=w*16+lr live in acc[m][0..3] of one lane, so the
// LSTM epilogue is in-register (only the Wo projection crosses waves).
// Ring-3 LDS: buffer (k+2)%3 was last read at iter k-1, and the single
// barrier at top of iter k already separates those reads from the chunk-k+2
// DMA issue -> one barrier per chunk. vmcnt(6) counted wait (chunk k landed,
// chunk k+1 in flight); vmcnt(0) only on the peeled final chunk.
// ---------------------------------------------------------------------------
__global__ __launch_bounds__(256, 2)
void lstm_kernel(const float* __restrict__ state, const float* __restrict__ action,
                 const float* __restrict__ hidden, const float* __restrict__ cell,
                 const short* __restrict__ Wt2, const float* __restrict__ bsum,
                 const float* __restrict__ Wo, const float* __restrict__ bo,
                 float* __restrict__ out, int Brows) {
    // LDS: B ring-3 [3][16 KB frag-linear] + A ring-3 [3][64 rows][128 B swz]
    __shared__ __align__(16) char smem[73728];
    char* const sB = smem;              // 3 * 16384
    char* const sA = smem + 49152;      // 3 * 8192

    const int t = threadIdx.x;
    const int w = t >> 6;
    const int l = t & 63;
    const int lr = l & 15;
    const int q = l >> 4;
    const int bm = blockIdx.x;

    // ---- A staging: wave w stages rows w*16..+16 per chunk (2 x 1 KB DMA).
    // Swizzle: LDS[row][g] = global[row][g ^ (row&7)] (16B granules) via
    // pre-swizzled SOURCE + linear DMA dest (rule #21).
    const int rsub = l >> 3;
    const int scol = (l & 7) ^ rsub;
    const char* aSrc[2];
    auto setA = [&](const float* p, int strideF) {
#pragma unroll
        for (int i = 0; i < 2; ++i) {
            size_t grow = (size_t)bm * 64 + w * 16 + i * 8 + rsub;
            aSrc[i] = (const char*)(p + grow * (size_t)strideF) + scol * 16;
        }
    };

    auto issueAB = [&](int buf, const char* bS) {
#pragma unroll
        for (int j = 0; j < 4; ++j)
            async16(bS + j * 1024, sB + buf * 16384 + (w * 4 + j) * 1024);
#pragma unroll
        for (int i = 0; i < 2; ++i) {
            async16(aSrc[i], sA + buf * 8192 + (w * 16 + i * 8) * 128);
            aSrc[i] += 128;   // next 32-k chunk within the same input buffer
        }
    };

    // accumulators preloaded with the fused gate bias (C-in of first MFMA)
    // acc[m][j]: rows m*16 + q*4 + r, col (w + 4j)*16 + lr  (gate j)
    float4_t acc[4][4];
#pragma unroll
    for (int m = 0; m < 4; ++m)
#pragma unroll
        for (int j = 0; j < 4; ++j)
            acc[m][j] = (float4_t)(bsum[(w + 4 * j) * 16 + lr]);

    // prologue: chunks 0 and 1 in flight (12 outstanding loads/wave)
    setA(state, 2048);
    const char* bSn = (const char*)Wt2 + (w * 4) * 1024 + l * 16;
    issueAB(0, bSn); bSn += 16384;
    issueAB(1, bSn); bSn += 16384;

    const char* const sAb = sA + lr * 128;            // + m*2048 + g*16
    const char* const sBb = sB + w * 1024 + l * 16;   // + j*4096
    const int g0 = (2 * q) ^ (lr & 7);
    const int g1 = g0 ^ 1;

    auto compute = [&](int buf) {
        const char* bufA = sAb + buf * 8192;
        const char* bufB = sBb + buf * 16384;
        short8 b[4], a[4];
#pragma unroll
        for (int j = 0; j < 4; ++j)
            b[j] = *(const short8*)(bufB + j * 4096);
#pragma unroll
        for (int m = 0; m < 4; ++m) {
            float4_t lo = *(const float4_t*)(bufA + m * 2048 + g0 * 16);
            float4_t hi = *(const float4_t*)(bufA + m * 2048 + g1 * 16);
            short8 av;
            av[0] = f2bf(lo[0]); av[1] = f2bf(lo[1]); av[2] = f2bf(lo[2]); av[3] = f2bf(lo[3]);
            av[4] = f2bf(hi[0]); av[5] = f2bf(hi[1]); av[6] = f2bf(hi[2]); av[7] = f2bf(hi[3]);
            a[m] = av;
        }
        __builtin_amdgcn_s_setprio(1);
#pragma unroll
        for (int m = 0; m < 4; ++m)
#pragma unroll
            for (int j = 0; j < 4; ++j)
                acc[m][j] = __builtin_amdgcn_mfma_f32_16x16x32_bf16(a[m], b[j], acc[m][j], 0, 0, 0);
        __builtin_amdgcn_s_setprio(0);
    };

    int cb = 0, ib = 2;   // compute / issue ring indices
    for (int k = 0; k < NCHUNK - 1; ++k) {
        // chunk k landed; chunk k+1's 6 loads stay in flight across barrier
        asm volatile("s_waitcnt vmcnt(6)" ::: "memory");
        __builtin_amdgcn_s_barrier();
        asm volatile("" ::: "memory");
        const int kk = k + 2;
        if (kk < NCHUNK) {
            if (kk == 64) setA(action, 512);  // state chunks 0..63
            if (kk == 80) setA(hidden, 64);   // action 64..79, hidden 80..81
            issueAB(ib, bSn);
            bSn += 16384;
            ib = (ib == 2) ? 0 : ib + 1;
        }
        compute(cb);
        cb = (cb == 2) ? 0 : cb + 1;
    }
    // last chunk: nothing newer in flight -> full drain is free
    asm volatile("s_waitcnt vmcnt(0)" ::: "memory");
    __builtin_amdgcn_s_barrier();
    asm volatile("" ::: "memory");
    compute(cb);

    // ---- LSTM epilogue ----
    // Gates of col n0 = w*16+lr are in-lane: i=acc[m][0], f=acc[m][1],
    // g=acc[m][2], o=acc[m][3]; rows m*16 + q*4 + r.
    const float bov = bo[0];
    const float wo = Wo[w * 16 + lr];
    const int n0 = w * 16 + lr;
    float* outH = out + Brows;
    float* outC = outH + (size_t)Brows * 64;
    float* sPart = (float*)smem;   // [64 rows][4 waves] partial Wo-dots

    __builtin_amdgcn_s_barrier();          // all k-loop LDS reads done
    asm volatile("" ::: "memory");

#pragma unroll
    for (int m = 0; m < 4; ++m) {
#pragma unroll
        for (int r = 0; r < 4; ++r) {
            const int row = m * 16 + q * 4 + r;
            const size_t grow = (size_t)bm * 64 + row;
            float i_t = sigmoid_fast(acc[m][0][r]);
            float f_t = sigmoid_fast(acc[m][1][r]);
            float g_t = tanh_fast(acc[m][2][r]);
            float o_t = sigmoid_fast(acc[m][3][r]);
            float c_t = f_t * cell[grow * 64 + n0] + i_t * g_t;
            float h_t = o_t * tanh_fast(c_t);
            outC[grow * 64 + n0] = c_t;
            outH[grow * 64 + n0] = h_t;
            float v = h_t * wo;
            v += __shfl_xor(v, 1);
            v += __shfl_xor(v, 2);
            v += __shfl_xor(v, 4);
            v += __shfl_xor(v, 8);
            if (lr == 0) sPart[row * 4 + w] = v;
        }
    }
    __syncthreads();
    if (t < 64) {
        float s = sPart[t * 4 + 0] + sPart[t * 4 + 1]
                + sPart[t * 4 + 2] + sPart[t * 4 + 3];
        out[(size_t)bm * 64 + t] = tanh_fast(s + bov);
    }
}

extern "C" void kernel_launch(void* const* d_in, const int* in_sizes, int n_in,
                              void* d_out, int out_size, void* d_ws, size_t ws_size,
                              hipStream_t stream) {
    const float* state  = (const float*)d_in[0];
    const float* action = (const float*)d_in[1];
    const float* hidden = (const float*)d_in[2];
    const float* cell   = (const float*)d_in[3];
    const float* Wi     = (const float*)d_in[4];
    const float* bi     = (const float*)d_in[5];
    const float* Wh     = (const float*)d_in[6];
    const float* bh     = (const float*)d_in[7];
    const float* Wo     = (const float*)d_in[8];
    const float* bo     = (const float*)d_in[9];

    const int Brows = in_sizes[0] / 2048;   // 32768

    short* Wt2  = (short*)d_ws;                                    // 82*8192 bf16
    float* bsum = (float*)((char*)d_ws + (size_t)NSTEP * 8192 * sizeof(short));

    prep_kernel<<<NSTEP, 256, 0, stream>>>(Wi, bi, Wh, bh, Wt2, bsum);
    lstm_kernel<<<Brows / 64, 256, 0, stream>>>(state, action, hidden, cell,
                                                Wt2, bsum, Wo, bo, (float*)d_out, Brows);
}